// Round 3
// baseline (604.884 us; speedup 1.0000x reference)
//
#include <hip/hip_runtime.h>
#include <cstdint>
#include <cstddef>

#define B_SZ 2
#define N_SEQ 32768
#define NB 2048
#define HD 32
#define LQ 16
#define KCNT 17
#define M_ROWS 65536
#define SCALE_F 0.17677669529663687f /* 32^-0.5 */

typedef __attribute__((ext_vector_type(8))) short sv8;
typedef __attribute__((ext_vector_type(4))) float f4;

__device__ __forceinline__ short f2bf(float f) {
  unsigned u = __builtin_bit_cast(unsigned, f);
  u = (u + 0x7FFFu + ((u >> 16) & 1u)) >> 16;
  return (short)u;
}
__device__ __forceinline__ float bf2f(short s) {
  unsigned u = ((unsigned)(unsigned short)s) << 16;
  return __builtin_bit_cast(float, u);
}
// 8 contiguous fp32 -> bf16 hi + residual-lo fragments (in registers)
__device__ __forceinline__ void split8(const float* __restrict__ p, sv8& hi, sv8& lo) {
  float4 f0 = *(const float4*)p, f1 = *(const float4*)(p + 4);
  float fv[8] = {f0.x, f0.y, f0.z, f0.w, f1.x, f1.y, f1.z, f1.w};
#pragma unroll
  for (int j = 0; j < 8; ++j) {
    short h = f2bf(fv[j]);
    hi[j] = h;
    lo[j] = f2bf(fv[j] - bf2f(h));
  }
}
__device__ __forceinline__ f4 mfma16(sv8 a, sv8 b, f4 c) {
  return __builtin_amdgcn_mfma_f32_16x16x32_bf16(a, b, c, 0, 0, 0);
}

// C[m,n] = sum_k X[m,k]*W[n,k] + bias[n] via split-bf16 (hh + lh + hl terms).
// Output routed: n in [0,256) -> Qb, [256,512) -> Kb, [512,768) -> Vb.
__global__ __launch_bounds__(256) void gemm_qkv(
    const float* __restrict__ X, const float* __restrict__ W,
    const float* __restrict__ bias, float* __restrict__ Qb,
    float* __restrict__ Kb, float* __restrict__ Vb) {
  const int tid = threadIdx.x, w = tid >> 6, l = tid & 63;
  const int wm = w >> 1, wn = w & 1;
  const int m0 = blockIdx.x * 128, n0 = blockIdx.y * 128;
  const int fr = l & 15, kg = (l >> 4) * 8;
  f4 acc[4][4] = {};
  for (int s = 0; s < 8; ++s) {
    const int k0 = s * 32 + kg;
    sv8 ah[4], al[4], bh[4], bl[4];
#pragma unroll
    for (int t = 0; t < 4; ++t) {
      split8(X + (size_t)(m0 + wm * 64 + t * 16 + fr) * 256 + k0, ah[t], al[t]);
      split8(W + (size_t)(n0 + wn * 64 + t * 16 + fr) * 256 + k0, bh[t], bl[t]);
    }
#pragma unroll
    for (int mt = 0; mt < 4; ++mt)
#pragma unroll
      for (int nt = 0; nt < 4; ++nt) {
        f4 a0 = acc[mt][nt];
        a0 = mfma16(ah[mt], bh[nt], a0);
        a0 = mfma16(al[mt], bh[nt], a0);
        a0 = mfma16(ah[mt], bl[nt], a0);
        acc[mt][nt] = a0;
      }
  }
  float* dst = (blockIdx.y < 2) ? Qb : ((blockIdx.y < 4) ? Kb : Vb);
  const int r0 = (l >> 4) * 4;
#pragma unroll
  for (int mt = 0; mt < 4; ++mt)
#pragma unroll
    for (int nt = 0; nt < 4; ++nt) {
      const int n = n0 + wn * 64 + nt * 16 + fr;
      const float bv = bias[n];
      const int nn = n & 255;
      const size_t mb = (size_t)(m0 + wm * 64 + mt * 16 + r0);
#pragma unroll
      for (int j = 0; j < 4; ++j) dst[(mb + j) * 256 + nn] = acc[mt][nt][j] + bv;
    }
}

// One block per (b, nb). Plain fp32 VALU attention (baseline-correct).
// Writes combined*V output as bf16 hi|lo [row][512] OVER the Q buffer.
__global__ __launch_bounds__(256) void attn_simple(
    const float* __restrict__ Qb, const float* __restrict__ Kb,
    const float* __restrict__ Vb, const int* __restrict__ amask,
    const float* __restrict__ efeat, const float* __restrict__ Wgate,
    const float* __restrict__ bgate, short* __restrict__ AO2) {
  __shared__ float Kf[KCNT][256];
  __shared__ float Vf[KCNT][256];
  const int tid = threadIdx.x, g = blockIdx.x;
  const int b = g >> 11, nb = g & (NB - 1);
  const size_t tok0 = (size_t)(b * N_SEQ + nb * LQ);
  // stage 16 leaf K,V rows (fp32)
#pragma unroll
  for (int i = 0; i < 4; ++i) {
    const int f = tid + i * 256;
    const int t = f >> 6, c = (f & 63) * 4;
    *(float4*)&Kf[t][c] = *(const float4*)(Kb + (tok0 + t) * 256 + c);
    *(float4*)&Vf[t][c] = *(const float4*)(Vb + (tok0 + t) * 256 + c);
  }
  __syncthreads();
  {  // block-node row = mean of the 16 leaf rows (linearity of Wk/Wv + bias)
    float ks = 0.f, vs = 0.f;
#pragma unroll
    for (int t = 0; t < 16; ++t) { ks += Kf[t][tid]; vs += Vf[t][tid]; }
    Kf[16][tid] = ks * 0.0625f;
    Vf[16][tid] = vs * 0.0625f;
  }
  __syncthreads();
  float comb[KCNT];
  int q = 0, h = 0;
  if (tid < 128) {
    q = tid >> 3; h = tid & 7;
    float qv[32];
#pragma unroll
    for (int d4 = 0; d4 < 8; ++d4) {
      float4 qq = *(const float4*)(Qb + (tok0 + q) * 256 + h * HD + d4 * 4);
      qv[d4 * 4] = qq.x; qv[d4 * 4 + 1] = qq.y;
      qv[d4 * 4 + 2] = qq.z; qv[d4 * 4 + 3] = qq.w;
    }
    const float wg0 = Wgate[h * 4], wg1 = Wgate[h * 4 + 1];
    const float wg2 = Wgate[h * 4 + 2], wg3 = Wgate[h * 4 + 3];
    const float bg = bgate[h];
    const float* eb = efeat + (size_t)(nb * LQ + q) * KCNT * 4;
    const int* mrow = amask + (size_t)(nb * LQ + q) * KCNT;
    float sc[KCNT], gt[KCNT];
    unsigned vis = 0;
    float mx = -1e30f;
#pragma unroll
    for (int kc = 0; kc < KCNT; ++kc) {
      float dot = 0.f;
#pragma unroll
      for (int d = 0; d < 32; ++d) dot += qv[d] * Kf[kc][h * HD + d];
      float e0, e1, e2, e3;
      if (kc == 16 || kc == q) { e0 = e1 = e2 = 0.f; e3 = 1.f; }
      else { float4 e = *(const float4*)(eb + kc * 4); e0 = e.x; e1 = e.y; e2 = e.z; e3 = e.w; }
      const int m = mrow[kc];
      const float s = dot * SCALE_F + e3;
      sc[kc] = s;
      if (m) { vis |= (1u << kc); mx = fmaxf(mx, s); }
      gt[kc] = m ? (e0 * wg0 + e1 * wg1 + e2 * wg2 + e3 * wg3 + bg) : 0.f;
    }
    float den = 0.f;
#pragma unroll
    for (int kc = 0; kc < KCNT; ++kc) {
      const float pv = (vis & (1u << kc)) ? expf(sc[kc] - mx) : 0.f;
      sc[kc] = pv;
      den += pv;
    }
    const float inv = 1.f / den;
#pragma unroll
    for (int kc = 0; kc < KCNT; ++kc) comb[kc] = sc[kc] * inv + gt[kc];
  }
  __syncthreads();  // ALL Q reads complete before AO2 overlays the Q buffer
  if (tid < 128) {
    short* ao = AO2 + (tok0 + q) * 512;
#pragma unroll
    for (int d = 0; d < 32; ++d) {
      float o = 0.f;
#pragma unroll
      for (int kc = 0; kc < KCNT; ++kc) o += comb[kc] * Vf[kc][h * HD + d];
      const short hi = f2bf(o);
      const short lo = f2bf(o - bf2f(hi));
      ao[h * HD + d] = hi;
      ao[256 + h * HD + d] = lo;
    }
  }
}

// C[m,n] = sum_k A[m,k]*Wp[n,k] + bias[n]; A pre-split [M][512] hi|lo shorts.
__global__ __launch_bounds__(256) void gemm_out(
    const short* __restrict__ A2, const float* __restrict__ W,
    const float* __restrict__ bias, float* __restrict__ C) {
  const int tid = threadIdx.x, w = tid >> 6, l = tid & 63;
  const int wm = w >> 1, wn = w & 1;
  const int m0 = blockIdx.x * 128, n0 = blockIdx.y * 128;
  const int fr = l & 15, kg = (l >> 4) * 8;
  f4 acc[4][4] = {};
  for (int s = 0; s < 8; ++s) {
    const int k0 = s * 32 + kg;
    sv8 ah[4], al[4], bh[4], bl[4];
#pragma unroll
    for (int t = 0; t < 4; ++t) {
      const short* ap = A2 + (size_t)(m0 + wm * 64 + t * 16 + fr) * 512 + k0;
      ah[t] = *(const sv8*)ap;
      al[t] = *(const sv8*)(ap + 256);
      split8(W + (size_t)(n0 + wn * 64 + t * 16 + fr) * 256 + k0, bh[t], bl[t]);
    }
#pragma unroll
    for (int mt = 0; mt < 4; ++mt)
#pragma unroll
      for (int nt = 0; nt < 4; ++nt) {
        f4 a0 = acc[mt][nt];
        a0 = mfma16(ah[mt], bh[nt], a0);
        a0 = mfma16(al[mt], bh[nt], a0);
        a0 = mfma16(ah[mt], bl[nt], a0);
        acc[mt][nt] = a0;
      }
  }
  const int r0 = (l >> 4) * 4;
#pragma unroll
  for (int mt = 0; mt < 4; ++mt)
#pragma unroll
    for (int nt = 0; nt < 4; ++nt) {
      const int n = n0 + wn * 64 + nt * 16 + fr;
      const float bv = bias[n];
      const size_t mb = (size_t)(m0 + wm * 64 + mt * 16 + r0);
#pragma unroll
      for (int j = 0; j < 4; ++j) C[(mb + j) * 256 + n] = acc[mt][nt][j] + bv;
    }
}

extern "C" void kernel_launch(void* const* d_in, const int* in_sizes, int n_in,
                              void* d_out, int out_size, void* d_ws, size_t ws_size,
                              hipStream_t stream) {
  const float* x = (const float*)d_in[0];
  const int* amask = (const int*)d_in[1];
  const float* efeat = (const float*)d_in[2];
  const float* Wqkv = (const float*)d_in[3];
  const float* bqkv = (const float*)d_in[4];
  const float* Wproj = (const float*)d_in[5];
  const float* bproj = (const float*)d_in[6];
  const float* Wgate = (const float*)d_in[7];
  const float* bgate = (const float*)d_in[8];
  float* out = (float*)d_out;

  // ws: Q fp32 [65536][256] (64 MiB, later overlaid by attn's hi|lo output)
  //     K fp32 [65536][256] (64 MiB).  V fp32 lives in d_out (exactly 64 MiB)
  //     and is dead before gemm_out overwrites it.  Total ws = 128 MiB.
  char* ws = (char*)d_ws;
  const size_t QSZ = (size_t)M_ROWS * 256 * 4;
  if (ws_size < 2 * QSZ) return;
  float* Qb = (float*)ws;
  float* Kb = (float*)(ws + QSZ);
  float* Vb = out;

  gemm_qkv<<<dim3(M_ROWS / 128, 6), 256, 0, stream>>>(x, Wqkv, bqkv, Qb, Kb, Vb);
  attn_simple<<<dim3(B_SZ * NB), 256, 0, stream>>>(Qb, Kb, Vb, amask, efeat,
                                                   Wgate, bgate, (short*)Qb);
  gemm_out<<<dim3(M_ROWS / 128, 2), 256, 0, stream>>>((const short*)Qb, Wproj,
                                                      bproj, out);
}

// Round 4
// 471.306 us; speedup vs baseline: 1.2834x; 1.2834x over previous
//
#include <hip/hip_runtime.h>
#include <cstdint>
#include <cstddef>

#define B_SZ 2
#define N_SEQ 32768
#define NB 2048
#define HD 32
#define LQ 16
#define KCNT 17
#define M_ROWS 65536
#define SCALE_F 0.17677669529663687f /* 32^-0.5 */

typedef __attribute__((ext_vector_type(8))) short sv8;
typedef __attribute__((ext_vector_type(4))) short sv4;
typedef __attribute__((ext_vector_type(4))) float f4;

__device__ __forceinline__ short f2bf(float f) {
  unsigned u = __builtin_bit_cast(unsigned, f);
  u = (u + 0x7FFFu + ((u >> 16) & 1u)) >> 16;
  return (short)u;
}
__device__ __forceinline__ float bf2f(short s) {
  unsigned u = ((unsigned)(unsigned short)s) << 16;
  return __builtin_bit_cast(float, u);
}
// 8 contiguous fp32 -> bf16 hi + residual-lo fragments (in registers)
__device__ __forceinline__ void split8(const float* __restrict__ p, sv8& hi, sv8& lo) {
  float4 f0 = *(const float4*)p, f1 = *(const float4*)(p + 4);
  float fv[8] = {f0.x, f0.y, f0.z, f0.w, f1.x, f1.y, f1.z, f1.w};
#pragma unroll
  for (int j = 0; j < 8; ++j) {
    short h = f2bf(fv[j]);
    hi[j] = h;
    lo[j] = f2bf(fv[j] - bf2f(h));
  }
}
__device__ __forceinline__ f4 mfma16(sv8 a, sv8 b, f4 c) {
  return __builtin_amdgcn_mfma_f32_16x16x32_bf16(a, b, c, 0, 0, 0);
}

// C[m,n] = sum_k X[m,k]*W[n,k] + bias[n] via split-bf16 (hh + lh + hl terms).
// Output routed: n in [0,256) -> Qb, [256,512) -> Kb, [512,768) -> Vb.
__global__ __launch_bounds__(256) void gemm_qkv(
    const float* __restrict__ X, const float* __restrict__ W,
    const float* __restrict__ bias, float* __restrict__ Qb,
    float* __restrict__ Kb, float* __restrict__ Vb) {
  const int tid = threadIdx.x, w = tid >> 6, l = tid & 63;
  const int wm = w >> 1, wn = w & 1;
  const int m0 = blockIdx.x * 128, n0 = blockIdx.y * 128;
  const int fr = l & 15, kg = (l >> 4) * 8;
  f4 acc[4][4] = {};
  for (int s = 0; s < 8; ++s) {
    const int k0 = s * 32 + kg;
    sv8 ah[4], al[4], bh[4], bl[4];
#pragma unroll
    for (int t = 0; t < 4; ++t) {
      split8(X + (size_t)(m0 + wm * 64 + t * 16 + fr) * 256 + k0, ah[t], al[t]);
      split8(W + (size_t)(n0 + wn * 64 + t * 16 + fr) * 256 + k0, bh[t], bl[t]);
    }
#pragma unroll
    for (int mt = 0; mt < 4; ++mt)
#pragma unroll
      for (int nt = 0; nt < 4; ++nt) {
        f4 a0 = acc[mt][nt];
        a0 = mfma16(ah[mt], bh[nt], a0);
        a0 = mfma16(al[mt], bh[nt], a0);
        a0 = mfma16(ah[mt], bl[nt], a0);
        acc[mt][nt] = a0;
      }
  }
  float* dst = (blockIdx.y < 2) ? Qb : ((blockIdx.y < 4) ? Kb : Vb);
  const int r0 = (l >> 4) * 4;
#pragma unroll
  for (int mt = 0; mt < 4; ++mt)
#pragma unroll
    for (int nt = 0; nt < 4; ++nt) {
      const int n = n0 + wn * 64 + nt * 16 + fr;
      const float bv = bias[n];
      const int nn = n & 255;
      const size_t mb = (size_t)(m0 + wm * 64 + mt * 16 + r0);
#pragma unroll
      for (int j = 0; j < 4; ++j) dst[(mb + j) * 256 + nn] = acc[mt][nt][j] + bv;
    }
}

#define KSTR 260  /* LDS row stride in floats: 1040 B == 16 mod 128 -> b128-friendly */

// One block per (b, nb). Fully thread-parallel fp32 attention.
// Phases: stage K/V/Q (float4) -> block-node mean -> scores (q,kc)x8h ->
// softmax+gate (q,h) -> PV (h,q,half). Output bf16 hi|lo overlays Q buffer.
__global__ __launch_bounds__(256) void attn_v2(
    const float* __restrict__ Qb, const float* __restrict__ Kb,
    const float* __restrict__ Vb, const int* __restrict__ amask,
    const float* __restrict__ efeat, const float* __restrict__ Wgate,
    const float* __restrict__ bgate, short* __restrict__ AO2) {
  __shared__ float Ks[KCNT * KSTR];
  __shared__ float Vs[KCNT * KSTR];
  __shared__ float Qs[LQ * KSTR];
  __shared__ float Sl[128 * KCNT];  // [q*8+h][kc], stride 17 (odd) -> 2-way max

  const int tid = threadIdx.x, g = blockIdx.x;
  const int b = g >> 11, nb = g & (NB - 1);
  const size_t tok0 = (size_t)(b * N_SEQ + nb * LQ);

  // --- stage: 16 rows x 64 float4 each of Q, K, V (coalesced) ---
#pragma unroll
  for (int i = 0; i < 4; ++i) {
    const int f = tid + i * 256;  // 0..1023
    const int t = f >> 6, c4 = (f & 63) * 4;
    *(float4*)&Ks[t * KSTR + c4] = *(const float4*)(Kb + (tok0 + t) * 256 + c4);
    *(float4*)&Vs[t * KSTR + c4] = *(const float4*)(Vb + (tok0 + t) * 256 + c4);
    *(float4*)&Qs[t * KSTR + c4] = *(const float4*)(Qb + (tok0 + t) * 256 + c4);
  }
  __syncthreads();
  {  // block-node row 16 = mean of 16 leaf rows (linearity of Wk/Wv + bias)
    float ks = 0.f, vs = 0.f;
#pragma unroll
    for (int t = 0; t < 16; ++t) {
      ks += Ks[t * KSTR + tid];
      vs += Vs[t * KSTR + tid];
    }
    Ks[16 * KSTR + tid] = ks * 0.0625f;
    Vs[16 * KSTR + tid] = vs * 0.0625f;
  }
  __syncthreads();

  // --- scores: thread (t = tid>>4, q = tid&15); kc = t (+16 for t==0) ---
  {
    const int t = tid >> 4, q = tid & 15;
    for (int kc = t; kc < KCNT; kc += 16) {
      float dot[8] = {};
#pragma unroll
      for (int h = 0; h < 8; ++h)
#pragma unroll
        for (int j = 0; j < 8; ++j) {
          float4 kv = *(const float4*)&Ks[kc * KSTR + h * 32 + j * 4];
          float4 qv = *(const float4*)&Qs[q * KSTR + h * 32 + j * 4];
          dot[h] += kv.x * qv.x + kv.y * qv.y + kv.z * qv.z + kv.w * qv.w;
        }
#pragma unroll
      for (int h = 0; h < 8; ++h) Sl[(q * 8 + h) * KCNT + kc] = dot[h];
    }
  }
  __syncthreads();

  // --- softmax + edge bias + gate -> combined weights (in-place in Sl) ---
  if (tid < 128) {
    const int q = tid >> 3, h = tid & 7;
    const float wg0 = Wgate[h * 4], wg1 = Wgate[h * 4 + 1];
    const float wg2 = Wgate[h * 4 + 2], wg3 = Wgate[h * 4 + 3];
    const float bg = bgate[h];
    const float* eb = efeat + (size_t)(nb * LQ + q) * KCNT * 4;
    const int* mrow = amask + (size_t)(nb * LQ + q) * KCNT;
    float sc[KCNT], gt[KCNT];
    unsigned vis = 0;
    float mx = -1e30f;
#pragma unroll
    for (int kc = 0; kc < KCNT; ++kc) {
      float e0, e1, e2, e3;
      if (kc == 16 || kc == q) { e0 = e1 = e2 = 0.f; e3 = 1.f; }
      else { float4 e = *(const float4*)(eb + kc * 4); e0 = e.x; e1 = e.y; e2 = e.z; e3 = e.w; }
      const int m = mrow[kc];
      const float s = Sl[tid * KCNT + kc] * SCALE_F + e3;
      sc[kc] = s;
      if (m) { vis |= (1u << kc); mx = fmaxf(mx, s); }
      gt[kc] = m ? (e0 * wg0 + e1 * wg1 + e2 * wg2 + e3 * wg3 + bg) : 0.f;
    }
    float den = 0.f;
#pragma unroll
    for (int kc = 0; kc < KCNT; ++kc) {
      const float pv = (vis & (1u << kc)) ? expf(sc[kc] - mx) : 0.f;
      sc[kc] = pv;
      den += pv;
    }
    const float inv = 1.f / den;
#pragma unroll
    for (int kc = 0; kc < KCNT; ++kc) Sl[tid * KCNT + kc] = sc[kc] * inv + gt[kc];
  }
  __syncthreads();

  // --- PV: thread (h = tid>>5, q = (tid>>1)&15, half = tid&1) -> 16 dims ---
  {
    const int h = tid >> 5, q = (tid >> 1) & 15, half = tid & 1;
    const int d0 = h * 32 + half * 16;
    float o[16] = {};
    for (int kc = 0; kc < KCNT; ++kc) {
      const float c = Sl[(q * 8 + h) * KCNT + kc];
#pragma unroll
      for (int j = 0; j < 4; ++j) {
        float4 vv = *(const float4*)&Vs[kc * KSTR + d0 + j * 4];
        o[j * 4] += c * vv.x;
        o[j * 4 + 1] += c * vv.y;
        o[j * 4 + 2] += c * vv.z;
        o[j * 4 + 3] += c * vv.w;
      }
    }
    short* ao = AO2 + (tok0 + q) * 512 + d0;
#pragma unroll
    for (int j = 0; j < 4; ++j) {
      sv4 hi, lo;
#pragma unroll
      for (int e = 0; e < 4; ++e) {
        const short hb = f2bf(o[j * 4 + e]);
        hi[e] = hb;
        lo[e] = f2bf(o[j * 4 + e] - bf2f(hb));
      }
      *(sv4*)&ao[j * 4] = hi;
      *(sv4*)&ao[256 + j * 4] = lo;
    }
  }
}

// C[m,n] = sum_k A[m,k]*Wp[n,k] + bias[n]; A pre-split [M][512] hi|lo shorts.
__global__ __launch_bounds__(256) void gemm_out(
    const short* __restrict__ A2, const float* __restrict__ W,
    const float* __restrict__ bias, float* __restrict__ C) {
  const int tid = threadIdx.x, w = tid >> 6, l = tid & 63;
  const int wm = w >> 1, wn = w & 1;
  const int m0 = blockIdx.x * 128, n0 = blockIdx.y * 128;
  const int fr = l & 15, kg = (l >> 4) * 8;
  f4 acc[4][4] = {};
  for (int s = 0; s < 8; ++s) {
    const int k0 = s * 32 + kg;
    sv8 ah[4], al[4], bh[4], bl[4];
#pragma unroll
    for (int t = 0; t < 4; ++t) {
      const short* ap = A2 + (size_t)(m0 + wm * 64 + t * 16 + fr) * 512 + k0;
      ah[t] = *(const sv8*)ap;
      al[t] = *(const sv8*)(ap + 256);
      split8(W + (size_t)(n0 + wn * 64 + t * 16 + fr) * 256 + k0, bh[t], bl[t]);
    }
#pragma unroll
    for (int mt = 0; mt < 4; ++mt)
#pragma unroll
      for (int nt = 0; nt < 4; ++nt) {
        f4 a0 = acc[mt][nt];
        a0 = mfma16(ah[mt], bh[nt], a0);
        a0 = mfma16(al[mt], bh[nt], a0);
        a0 = mfma16(ah[mt], bl[nt], a0);
        acc[mt][nt] = a0;
      }
  }
  const int r0 = (l >> 4) * 4;
#pragma unroll
  for (int mt = 0; mt < 4; ++mt)
#pragma unroll
    for (int nt = 0; nt < 4; ++nt) {
      const int n = n0 + wn * 64 + nt * 16 + fr;
      const float bv = bias[n];
      const size_t mb = (size_t)(m0 + wm * 64 + mt * 16 + r0);
#pragma unroll
      for (int j = 0; j < 4; ++j) C[(mb + j) * 256 + n] = acc[mt][nt][j] + bv;
    }
}

extern "C" void kernel_launch(void* const* d_in, const int* in_sizes, int n_in,
                              void* d_out, int out_size, void* d_ws, size_t ws_size,
                              hipStream_t stream) {
  const float* x = (const float*)d_in[0];
  const int* amask = (const int*)d_in[1];
  const float* efeat = (const float*)d_in[2];
  const float* Wqkv = (const float*)d_in[3];
  const float* bqkv = (const float*)d_in[4];
  const float* Wproj = (const float*)d_in[5];
  const float* bproj = (const float*)d_in[6];
  const float* Wgate = (const float*)d_in[7];
  const float* bgate = (const float*)d_in[8];
  float* out = (float*)d_out;

  // ws: Q fp32 [65536][256] (64 MiB, later overlaid by attn's hi|lo output)
  //     K fp32 [65536][256] (64 MiB).  V fp32 lives in d_out (exactly 64 MiB)
  //     and is dead before gemm_out overwrites it.  Total ws = 128 MiB.
  char* ws = (char*)d_ws;
  const size_t QSZ = (size_t)M_ROWS * 256 * 4;
  if (ws_size < 2 * QSZ) return;
  float* Qb = (float*)ws;
  float* Kb = (float*)(ws + QSZ);
  float* Vb = out;

  gemm_qkv<<<dim3(M_ROWS / 128, 6), 256, 0, stream>>>(x, Wqkv, bqkv, Qb, Kb, Vb);
  attn_v2<<<dim3(B_SZ * NB), 256, 0, stream>>>(Qb, Kb, Vb, amask, efeat,
                                               Wgate, bgate, (short*)Qb);
  gemm_out<<<dim3(M_ROWS / 128, 2), 256, 0, stream>>>((const short*)Qb, Wproj,
                                                      bproj, out);
}

// Round 5
// 366.523 us; speedup vs baseline: 1.6503x; 1.2859x over previous
//
#include <hip/hip_runtime.h>
#include <cstdint>
#include <cstddef>

#define B_SZ 2
#define N_SEQ 32768
#define NB 2048
#define HD 32
#define LQ 16
#define KCNT 17
#define M_ROWS 65536
#define SCALE_F 0.17677669529663687f /* 32^-0.5 */

typedef __attribute__((ext_vector_type(8))) short sv8;
typedef __attribute__((ext_vector_type(4))) short sv4;
typedef __attribute__((ext_vector_type(4))) float f4;

__device__ __forceinline__ short f2bf(float f) {
  unsigned u = __builtin_bit_cast(unsigned, f);
  u = (u + 0x7FFFu + ((u >> 16) & 1u)) >> 16;
  return (short)u;
}
__device__ __forceinline__ float bf2f(short s) {
  unsigned u = ((unsigned)(unsigned short)s) << 16;
  return __builtin_bit_cast(float, u);
}
__device__ __forceinline__ void split8(const float* __restrict__ p, sv8& hi, sv8& lo) {
  float4 f0 = *(const float4*)p, f1 = *(const float4*)(p + 4);
  float fv[8] = {f0.x, f0.y, f0.z, f0.w, f1.x, f1.y, f1.z, f1.w};
#pragma unroll
  for (int j = 0; j < 8; ++j) {
    short h = f2bf(fv[j]);
    hi[j] = h;
    lo[j] = f2bf(fv[j] - bf2f(h));
  }
}
__device__ __forceinline__ void gload16(const void* g, void* l) {
  __builtin_amdgcn_global_load_lds(
      (const __attribute__((address_space(1))) unsigned int*)g,
      (__attribute__((address_space(3))) unsigned int*)l, 16, 0, 0);
}
__device__ __forceinline__ f4 mfma16(sv8 a, sv8 b, f4 c) {
  return __builtin_amdgcn_mfma_f32_16x16x32_bf16(a, b, c, 0, 0, 0);
}

// fp32 [rows][256] -> bf16 hi|lo [rows][512]
__global__ __launch_bounds__(256) void split256(const float* __restrict__ src,
                                                short* __restrict__ dst, int n4) {
  int i = blockIdx.x * 256 + threadIdx.x;
  if (i >= n4) return;
  float4 v = ((const float4*)src)[i];
  size_t row = (size_t)(i >> 6);
  int c = (i & 63) * 4;
  float fv[4] = {v.x, v.y, v.z, v.w};
  sv4 hi, lo;
#pragma unroll
  for (int j = 0; j < 4; ++j) {
    short h, l2;
    l2 = 0;
    h = f2bf(fv[j]);
    l2 = f2bf(fv[j] - bf2f(h));
    hi[j] = h;
    lo[j] = l2;
  }
  *(sv4*)&dst[row * 512 + c] = hi;
  *(sv4*)&dst[row * 512 + 256 + c] = lo;
}

// ---- Path A: pre-split GEMM, m97 structure (LDS staging, no conversion VALU).
// A2/B2: [rows][512] bf16 hi|lo. K' = 24 steps of 32: hh(0-7) lh(8-15) hl(16-23).
// Body shared; two epilogues (QKV routing vs plain).
#define GEMM_PRE_BODY                                                          \
  __shared__ __align__(16) short As[128][32];                                  \
  __shared__ __align__(16) short Bs[128][32];                                  \
  const int tid = threadIdx.x;                                                 \
  const int w = tid >> 6, l = tid & 63;                                        \
  const int wm = w >> 1, wn = w & 1;                                           \
  const int m0 = blockIdx.x * 128, n0 = blockIdx.y * 128;                      \
  const int lr = l >> 2;                                                       \
  const int lc = (l & 3) * 8;                                                  \
  f4 acc[4][4] = {};                                                           \
  for (int s = 0; s < 24; ++s) {                                               \
    const int sk = (s & 7) * 32;                                               \
    const int ka = ((s >= 8 && s < 16) ? 256 : 0) + sk;                        \
    const int kb = ((s >= 16) ? 256 : 0) + sk;                                 \
    _Pragma("unroll") for (int i = 0; i < 2; ++i) {                            \
      const int row = w * 32 + i * 16;                                         \
      gload16(A2 + (size_t)(m0 + row + lr) * 512 + ka + lc, (void*)&As[row][0]);\
      gload16(B2 + (size_t)(n0 + row + lr) * 512 + kb + lc, (void*)&Bs[row][0]);\
    }                                                                          \
    __syncthreads();                                                           \
    const int fr = l & 15, kg = (l >> 4) * 8;                                  \
    sv8 a[4], bb[4];                                                           \
    _Pragma("unroll") for (int t = 0; t < 4; ++t) {                            \
      a[t] = *(const sv8*)&As[wm * 64 + t * 16 + fr][kg];                      \
      bb[t] = *(const sv8*)&Bs[wn * 64 + t * 16 + fr][kg];                     \
    }                                                                          \
    _Pragma("unroll") for (int mt = 0; mt < 4; ++mt)                           \
      _Pragma("unroll") for (int nt = 0; nt < 4; ++nt)                         \
        acc[mt][nt] = mfma16(a[mt], bb[nt], acc[mt][nt]);                      \
    __syncthreads();                                                           \
  }

__global__ __launch_bounds__(256) void gemm_pre_qkv(
    const short* __restrict__ A2, const short* __restrict__ B2,
    const float* __restrict__ bias, float* __restrict__ Qb,
    float* __restrict__ Kb, float* __restrict__ Vb) {
  GEMM_PRE_BODY
  float* dst = (blockIdx.y < 2) ? Qb : ((blockIdx.y < 4) ? Kb : Vb);
  const int fr2 = l & 15, r0 = (l >> 4) * 4;
#pragma unroll
  for (int mt = 0; mt < 4; ++mt)
#pragma unroll
    for (int nt = 0; nt < 4; ++nt) {
      const int n = n0 + wn * 64 + nt * 16 + fr2;
      const float bv = bias[n];
      const int nn = n & 255;
      const size_t mb = (size_t)(m0 + wm * 64 + mt * 16 + r0);
#pragma unroll
      for (int j = 0; j < 4; ++j) dst[(mb + j) * 256 + nn] = acc[mt][nt][j] + bv;
    }
}

__global__ __launch_bounds__(256) void gemm_pre_out(
    const short* __restrict__ A2, const short* __restrict__ B2,
    const float* __restrict__ bias, float* __restrict__ C) {
  GEMM_PRE_BODY
  const int fr2 = l & 15, r0 = (l >> 4) * 4;
#pragma unroll
  for (int mt = 0; mt < 4; ++mt)
#pragma unroll
    for (int nt = 0; nt < 4; ++nt) {
      const int n = n0 + wn * 64 + nt * 16 + fr2;
      const float bv = bias[n];
      const size_t mb = (size_t)(m0 + wm * 64 + mt * 16 + r0);
#pragma unroll
      for (int j = 0; j < 4; ++j) C[(mb + j) * 256 + n] = acc[mt][nt][j] + bv;
    }
}

// ---- Path B fallback: round-4 on-the-fly-split GEMMs (proven) ----
__global__ __launch_bounds__(256) void gemm_qkv(
    const float* __restrict__ X, const float* __restrict__ W,
    const float* __restrict__ bias, float* __restrict__ Qb,
    float* __restrict__ Kb, float* __restrict__ Vb) {
  const int tid = threadIdx.x, w = tid >> 6, l = tid & 63;
  const int wm = w >> 1, wn = w & 1;
  const int m0 = blockIdx.x * 128, n0 = blockIdx.y * 128;
  const int fr = l & 15, kg = (l >> 4) * 8;
  f4 acc[4][4] = {};
  for (int s = 0; s < 8; ++s) {
    const int k0 = s * 32 + kg;
    sv8 ah[4], al[4], bh[4], bl[4];
#pragma unroll
    for (int t = 0; t < 4; ++t) {
      split8(X + (size_t)(m0 + wm * 64 + t * 16 + fr) * 256 + k0, ah[t], al[t]);
      split8(W + (size_t)(n0 + wn * 64 + t * 16 + fr) * 256 + k0, bh[t], bl[t]);
    }
#pragma unroll
    for (int mt = 0; mt < 4; ++mt)
#pragma unroll
      for (int nt = 0; nt < 4; ++nt) {
        f4 a0 = acc[mt][nt];
        a0 = mfma16(ah[mt], bh[nt], a0);
        a0 = mfma16(al[mt], bh[nt], a0);
        a0 = mfma16(ah[mt], bl[nt], a0);
        acc[mt][nt] = a0;
      }
  }
  float* dst = (blockIdx.y < 2) ? Qb : ((blockIdx.y < 4) ? Kb : Vb);
  const int r0 = (l >> 4) * 4;
#pragma unroll
  for (int mt = 0; mt < 4; ++mt)
#pragma unroll
    for (int nt = 0; nt < 4; ++nt) {
      const int n = n0 + wn * 64 + nt * 16 + fr;
      const float bv = bias[n];
      const int nn = n & 255;
      const size_t mb = (size_t)(m0 + wm * 64 + mt * 16 + r0);
#pragma unroll
      for (int j = 0; j < 4; ++j) dst[(mb + j) * 256 + nn] = acc[mt][nt][j] + bv;
    }
}

__global__ __launch_bounds__(256) void gemm_out(
    const short* __restrict__ A2, const float* __restrict__ W,
    const float* __restrict__ bias, float* __restrict__ C) {
  const int tid = threadIdx.x, w = tid >> 6, l = tid & 63;
  const int wm = w >> 1, wn = w & 1;
  const int m0 = blockIdx.x * 128, n0 = blockIdx.y * 128;
  const int fr = l & 15, kg = (l >> 4) * 8;
  f4 acc[4][4] = {};
  for (int s = 0; s < 8; ++s) {
    const int k0 = s * 32 + kg;
    sv8 ah[4], al[4], bh[4], bl[4];
#pragma unroll
    for (int t = 0; t < 4; ++t) {
      const short* ap = A2 + (size_t)(m0 + wm * 64 + t * 16 + fr) * 512 + k0;
      ah[t] = *(const sv8*)ap;
      al[t] = *(const sv8*)(ap + 256);
      split8(W + (size_t)(n0 + wn * 64 + t * 16 + fr) * 256 + k0, bh[t], bl[t]);
    }
#pragma unroll
    for (int mt = 0; mt < 4; ++mt)
#pragma unroll
      for (int nt = 0; nt < 4; ++nt) {
        f4 a0 = acc[mt][nt];
        a0 = mfma16(ah[mt], bh[nt], a0);
        a0 = mfma16(al[mt], bh[nt], a0);
        a0 = mfma16(ah[mt], bl[nt], a0);
        acc[mt][nt] = a0;
      }
  }
  const int r0 = (l >> 4) * 4;
#pragma unroll
  for (int mt = 0; mt < 4; ++mt)
#pragma unroll
    for (int nt = 0; nt < 4; ++nt) {
      const int n = n0 + wn * 64 + nt * 16 + fr;
      const float bv = bias[n];
      const size_t mb = (size_t)(m0 + wm * 64 + mt * 16 + r0);
#pragma unroll
      for (int j = 0; j < 4; ++j) C[(mb + j) * 256 + n] = acc[mt][nt][j] + bv;
    }
}

#define KSTR 260 /* LDS row stride in floats: 1040 B == 16 mod 128 */

// One block per (b, nb). Fully thread-parallel fp32 attention.
__global__ __launch_bounds__(256) void attn_v2(
    const float* __restrict__ Qb, const float* __restrict__ Kb,
    const float* __restrict__ Vb, const int* __restrict__ amask,
    const float* __restrict__ efeat, const float* __restrict__ Wgate,
    const float* __restrict__ bgate, short* __restrict__ AO2) {
  __shared__ float Ks[KCNT * KSTR];
  __shared__ float Vs[KCNT * KSTR];
  __shared__ float Qs[LQ * KSTR];
  __shared__ float Sl[128 * KCNT];

  const int tid = threadIdx.x, g = blockIdx.x;
  const int b = g >> 11, nb = g & (NB - 1);
  const size_t tok0 = (size_t)(b * N_SEQ + nb * LQ);

#pragma unroll
  for (int i = 0; i < 4; ++i) {
    const int f = tid + i * 256;
    const int t = f >> 6, c4 = (f & 63) * 4;
    *(float4*)&Ks[t * KSTR + c4] = *(const float4*)(Kb + (tok0 + t) * 256 + c4);
    *(float4*)&Vs[t * KSTR + c4] = *(const float4*)(Vb + (tok0 + t) * 256 + c4);
    *(float4*)&Qs[t * KSTR + c4] = *(const float4*)(Qb + (tok0 + t) * 256 + c4);
  }
  __syncthreads();
  {
    float ks = 0.f, vs = 0.f;
#pragma unroll
    for (int t = 0; t < 16; ++t) {
      ks += Ks[t * KSTR + tid];
      vs += Vs[t * KSTR + tid];
    }
    Ks[16 * KSTR + tid] = ks * 0.0625f;
    Vs[16 * KSTR + tid] = vs * 0.0625f;
  }
  __syncthreads();
  {
    const int t = tid >> 4, q = tid & 15;
    for (int kc = t; kc < KCNT; kc += 16) {
      float dot[8] = {};
#pragma unroll
      for (int h = 0; h < 8; ++h)
#pragma unroll
        for (int j = 0; j < 8; ++j) {
          float4 kv = *(const float4*)&Ks[kc * KSTR + h * 32 + j * 4];
          float4 qv = *(const float4*)&Qs[q * KSTR + h * 32 + j * 4];
          dot[h] += kv.x * qv.x + kv.y * qv.y + kv.z * qv.z + kv.w * qv.w;
        }
#pragma unroll
      for (int h = 0; h < 8; ++h) Sl[(q * 8 + h) * KCNT + kc] = dot[h];
    }
  }
  __syncthreads();
  if (tid < 128) {
    const int q = tid >> 3, h = tid & 7;
    const float wg0 = Wgate[h * 4], wg1 = Wgate[h * 4 + 1];
    const float wg2 = Wgate[h * 4 + 2], wg3 = Wgate[h * 4 + 3];
    const float bg = bgate[h];
    const float* eb = efeat + (size_t)(nb * LQ + q) * KCNT * 4;
    const int* mrow = amask + (size_t)(nb * LQ + q) * KCNT;
    float sc[KCNT], gt[KCNT];
    unsigned vis = 0;
    float mx = -1e30f;
#pragma unroll
    for (int kc = 0; kc < KCNT; ++kc) {
      float e0, e1, e2, e3;
      if (kc == 16 || kc == q) { e0 = e1 = e2 = 0.f; e3 = 1.f; }
      else { float4 e = *(const float4*)(eb + kc * 4); e0 = e.x; e1 = e.y; e2 = e.z; e3 = e.w; }
      const int m = mrow[kc];
      const float s = Sl[tid * KCNT + kc] * SCALE_F + e3;
      sc[kc] = s;
      if (m) { vis |= (1u << kc); mx = fmaxf(mx, s); }
      gt[kc] = m ? (e0 * wg0 + e1 * wg1 + e2 * wg2 + e3 * wg3 + bg) : 0.f;
    }
    float den = 0.f;
#pragma unroll
    for (int kc = 0; kc < KCNT; ++kc) {
      const float pv = (vis & (1u << kc)) ? expf(sc[kc] - mx) : 0.f;
      sc[kc] = pv;
      den += pv;
    }
    const float inv = 1.f / den;
#pragma unroll
    for (int kc = 0; kc < KCNT; ++kc) Sl[tid * KCNT + kc] = sc[kc] * inv + gt[kc];
  }
  __syncthreads();
  {
    const int h = tid >> 5, q = (tid >> 1) & 15, half = tid & 1;
    const int d0 = h * 32 + half * 16;
    float o[16] = {};
    for (int kc = 0; kc < KCNT; ++kc) {
      const float c = Sl[(q * 8 + h) * KCNT + kc];
#pragma unroll
      for (int j = 0; j < 4; ++j) {
        float4 vv = *(const float4*)&Vs[kc * KSTR + d0 + j * 4];
        o[j * 4] += c * vv.x;
        o[j * 4 + 1] += c * vv.y;
        o[j * 4 + 2] += c * vv.z;
        o[j * 4 + 3] += c * vv.w;
      }
    }
    short* ao = AO2 + (tok0 + q) * 512 + d0;
#pragma unroll
    for (int j = 0; j < 4; ++j) {
      sv4 hi, lo;
#pragma unroll
      for (int e = 0; e < 4; ++e) {
        const short hb = f2bf(o[j * 4 + e]);
        hi[e] = hb;
        lo[e] = f2bf(o[j * 4 + e] - bf2f(hb));
      }
      *(sv4*)&ao[j * 4] = hi;
      *(sv4*)&ao[256 + j * 4] = lo;
    }
  }
}

extern "C" void kernel_launch(void* const* d_in, const int* in_sizes, int n_in,
                              void* d_out, int out_size, void* d_ws, size_t ws_size,
                              hipStream_t stream) {
  const float* x = (const float*)d_in[0];
  const int* amask = (const int*)d_in[1];
  const float* efeat = (const float*)d_in[2];
  const float* Wqkv = (const float*)d_in[3];
  const float* bqkv = (const float*)d_in[4];
  const float* Wproj = (const float*)d_in[5];
  const float* bproj = (const float*)d_in[6];
  const float* Wgate = (const float*)d_in[7];
  const float* bgate = (const float*)d_in[8];
  float* out = (float*)d_out;

  char* ws = (char*)d_ws;
  const size_t QSZ = (size_t)M_ROWS * 256 * 4;  // 64 MiB
  const size_t W2Q_SZ = (size_t)768 * 512 * 2;  // 768 KiB
  const size_t W2P_SZ = (size_t)256 * 512 * 2;  // 256 KiB

  if (ws_size >= 3 * QSZ + W2Q_SZ + W2P_SZ) {
    // Path A (expected; ws >= ~193 MiB): pre-split everything, m97 GEMMs.
    short* X2 = (short*)ws;                       // 64 MiB
    float* Qb = (float*)(ws + QSZ);               // 64 MiB (AO2 overlays)
    float* Kb = (float*)(ws + 2 * QSZ);           // 64 MiB
    short* W2Q = (short*)(ws + 3 * QSZ);
    short* W2P = (short*)(ws + 3 * QSZ + W2Q_SZ);
    float* Vb = out;
    split256<<<dim3(M_ROWS * 64 / 256), 256, 0, stream>>>(x, X2, M_ROWS * 64);
    split256<<<dim3(768 * 64 / 256), 256, 0, stream>>>(Wqkv, W2Q, 768 * 64);
    split256<<<dim3(256 * 64 / 256), 256, 0, stream>>>(Wproj, W2P, 256 * 64);
    gemm_pre_qkv<<<dim3(M_ROWS / 128, 6), 256, 0, stream>>>(X2, W2Q, bqkv, Qb, Kb, Vb);
    attn_v2<<<dim3(B_SZ * NB), 256, 0, stream>>>(Qb, Kb, Vb, amask, efeat,
                                                 Wgate, bgate, (short*)Qb);
    gemm_pre_out<<<dim3(M_ROWS / 128, 2), 256, 0, stream>>>((const short*)Qb,
                                                            W2P, bproj, out);
  } else {
    // Path B fallback (ws >= 128 MiB): round-4 proven pipeline.
    if (ws_size < 2 * QSZ) return;
    float* Qb = (float*)ws;
    float* Kb = (float*)(ws + QSZ);
    float* Vb = out;
    gemm_qkv<<<dim3(M_ROWS / 128, 6), 256, 0, stream>>>(x, Wqkv, bqkv, Qb, Kb, Vb);
    attn_v2<<<dim3(B_SZ * NB), 256, 0, stream>>>(Qb, Kb, Vb, amask, efeat,
                                                 Wgate, bgate, (short*)Qb);
    gemm_out<<<dim3(M_ROWS / 128, 2), 256, 0, stream>>>((const short*)Qb, Wproj,
                                                        bproj, out);
  }
}

// Round 6
// 305.050 us; speedup vs baseline: 1.9829x; 1.2015x over previous
//
#include <hip/hip_runtime.h>
#include <cstdint>
#include <cstddef>

#define B_SZ 2
#define N_SEQ 32768
#define NB 2048
#define HD 32
#define LQ 16
#define KCNT 17
#define M_ROWS 65536
#define SCALE_F 0.17677669529663687f /* 32^-0.5 */

typedef __attribute__((ext_vector_type(8))) short sv8;
typedef __attribute__((ext_vector_type(4))) short sv4;
typedef __attribute__((ext_vector_type(4))) float f4;

__device__ __forceinline__ short f2bf(float f) {
  unsigned u = __builtin_bit_cast(unsigned, f);
  u = (u + 0x7FFFu + ((u >> 16) & 1u)) >> 16;
  return (short)u;
}
__device__ __forceinline__ float bf2f(short s) {
  unsigned u = ((unsigned)(unsigned short)s) << 16;
  return __builtin_bit_cast(float, u);
}
__device__ __forceinline__ void split8(const float* __restrict__ p, sv8& hi, sv8& lo) {
  float4 f0 = *(const float4*)p, f1 = *(const float4*)(p + 4);
  float fv[8] = {f0.x, f0.y, f0.z, f0.w, f1.x, f1.y, f1.z, f1.w};
#pragma unroll
  for (int j = 0; j < 8; ++j) {
    short h = f2bf(fv[j]);
    hi[j] = h;
    lo[j] = f2bf(fv[j] - bf2f(h));
  }
}
__device__ __forceinline__ void gload16(const void* g, void* l) {
  __builtin_amdgcn_global_load_lds(
      (const __attribute__((address_space(1))) unsigned int*)g,
      (__attribute__((address_space(3))) unsigned int*)l, 16, 0, 0);
}
__device__ __forceinline__ f4 mfma16(sv8 a, sv8 b, f4 c) {
  return __builtin_amdgcn_mfma_f32_16x16x32_bf16(a, b, c, 0, 0, 0);
}

// fp32 [rows][256] -> bf16 hi|lo [rows][512]
__global__ __launch_bounds__(256) void split256(const float* __restrict__ src,
                                                short* __restrict__ dst, int n4) {
  int i = blockIdx.x * 256 + threadIdx.x;
  if (i >= n4) return;
  float4 v = ((const float4*)src)[i];
  size_t row = (size_t)(i >> 6);
  int c = (i & 63) * 4;
  float fv[4] = {v.x, v.y, v.z, v.w};
  sv4 hi, lo;
#pragma unroll
  for (int j = 0; j < 4; ++j) {
    short h = f2bf(fv[j]);
    hi[j] = h;
    lo[j] = f2bf(fv[j] - bf2f(h));
  }
  *(sv4*)&dst[row * 512 + c] = hi;
  *(sv4*)&dst[row * 512 + 256 + c] = lo;
}

// ---- pre-split GEMM, m97 structure (unchanged from round 5) ----
#define GEMM_PRE_BODY                                                          \
  __shared__ __align__(16) short As[128][32];                                  \
  __shared__ __align__(16) short Bs[128][32];                                  \
  const int tid = threadIdx.x;                                                 \
  const int w = tid >> 6, l = tid & 63;                                        \
  const int wm = w >> 1, wn = w & 1;                                           \
  const int m0 = blockIdx.x * 128, n0 = blockIdx.y * 128;                      \
  const int lr = l >> 2;                                                       \
  const int lc = (l & 3) * 8;                                                  \
  f4 acc[4][4] = {};                                                           \
  for (int s = 0; s < 24; ++s) {                                               \
    const int sk = (s & 7) * 32;                                               \
    const int ka = ((s >= 8 && s < 16) ? 256 : 0) + sk;                        \
    const int kb = ((s >= 16) ? 256 : 0) + sk;                                 \
    _Pragma("unroll") for (int i = 0; i < 2; ++i) {                            \
      const int row = w * 32 + i * 16;                                         \
      gload16(A2 + (size_t)(m0 + row + lr) * 512 + ka + lc, (void*)&As[row][0]);\
      gload16(B2 + (size_t)(n0 + row + lr) * 512 + kb + lc, (void*)&Bs[row][0]);\
    }                                                                          \
    __syncthreads();                                                           \
    const int fr = l & 15, kg = (l >> 4) * 8;                                  \
    sv8 a[4], bb[4];                                                           \
    _Pragma("unroll") for (int t = 0; t < 4; ++t) {                            \
      a[t] = *(const sv8*)&As[wm * 64 + t * 16 + fr][kg];                      \
      bb[t] = *(const sv8*)&Bs[wn * 64 + t * 16 + fr][kg];                     \
    }                                                                          \
    _Pragma("unroll") for (int mt = 0; mt < 4; ++mt)                           \
      _Pragma("unroll") for (int nt = 0; nt < 4; ++nt)                         \
        acc[mt][nt] = mfma16(a[mt], bb[nt], acc[mt][nt]);                      \
    __syncthreads();                                                           \
  }

__global__ __launch_bounds__(256) void gemm_pre_qkv(
    const short* __restrict__ A2, const short* __restrict__ B2,
    const float* __restrict__ bias, float* __restrict__ Qb,
    float* __restrict__ Kb, float* __restrict__ Vb) {
  GEMM_PRE_BODY
  float* dst = (blockIdx.y < 2) ? Qb : ((blockIdx.y < 4) ? Kb : Vb);
  const int fr2 = l & 15, r0 = (l >> 4) * 4;
#pragma unroll
  for (int mt = 0; mt < 4; ++mt)
#pragma unroll
    for (int nt = 0; nt < 4; ++nt) {
      const int n = n0 + wn * 64 + nt * 16 + fr2;
      const float bv = bias[n];
      const int nn = n & 255;
      const size_t mb = (size_t)(m0 + wm * 64 + mt * 16 + r0);
#pragma unroll
      for (int j = 0; j < 4; ++j) dst[(mb + j) * 256 + nn] = acc[mt][nt][j] + bv;
    }
}

__global__ __launch_bounds__(256) void gemm_pre_out(
    const short* __restrict__ A2, const short* __restrict__ B2,
    const float* __restrict__ bias, float* __restrict__ C) {
  GEMM_PRE_BODY
  const int fr2 = l & 15, r0 = (l >> 4) * 4;
#pragma unroll
  for (int mt = 0; mt < 4; ++mt)
#pragma unroll
    for (int nt = 0; nt < 4; ++nt) {
      const int n = n0 + wn * 64 + nt * 16 + fr2;
      const float bv = bias[n];
      const size_t mb = (size_t)(m0 + wm * 64 + mt * 16 + r0);
#pragma unroll
      for (int j = 0; j < 4; ++j) C[(mb + j) * 256 + n] = acc[mt][nt][j] + bv;
    }
}

// ---- fallback on-the-fly-split GEMMs (proven round 4) ----
__global__ __launch_bounds__(256) void gemm_qkv(
    const float* __restrict__ X, const float* __restrict__ W,
    const float* __restrict__ bias, float* __restrict__ Qb,
    float* __restrict__ Kb, float* __restrict__ Vb) {
  const int tid = threadIdx.x, w = tid >> 6, l = tid & 63;
  const int wm = w >> 1, wn = w & 1;
  const int m0 = blockIdx.x * 128, n0 = blockIdx.y * 128;
  const int fr = l & 15, kg = (l >> 4) * 8;
  f4 acc[4][4] = {};
  for (int s = 0; s < 8; ++s) {
    const int k0 = s * 32 + kg;
    sv8 ah[4], al[4], bh[4], bl[4];
#pragma unroll
    for (int t = 0; t < 4; ++t) {
      split8(X + (size_t)(m0 + wm * 64 + t * 16 + fr) * 256 + k0, ah[t], al[t]);
      split8(W + (size_t)(n0 + wn * 64 + t * 16 + fr) * 256 + k0, bh[t], bl[t]);
    }
#pragma unroll
    for (int mt = 0; mt < 4; ++mt)
#pragma unroll
      for (int nt = 0; nt < 4; ++nt) {
        f4 a0 = acc[mt][nt];
        a0 = mfma16(ah[mt], bh[nt], a0);
        a0 = mfma16(al[mt], bh[nt], a0);
        a0 = mfma16(ah[mt], bl[nt], a0);
        acc[mt][nt] = a0;
      }
  }
  float* dst = (blockIdx.y < 2) ? Qb : ((blockIdx.y < 4) ? Kb : Vb);
  const int r0 = (l >> 4) * 4;
#pragma unroll
  for (int mt = 0; mt < 4; ++mt)
#pragma unroll
    for (int nt = 0; nt < 4; ++nt) {
      const int n = n0 + wn * 64 + nt * 16 + fr;
      const float bv = bias[n];
      const int nn = n & 255;
      const size_t mb = (size_t)(m0 + wm * 64 + mt * 16 + r0);
#pragma unroll
      for (int j = 0; j < 4; ++j) dst[(mb + j) * 256 + nn] = acc[mt][nt][j] + bv;
    }
}

__global__ __launch_bounds__(256) void gemm_out(
    const short* __restrict__ A2, const float* __restrict__ W,
    const float* __restrict__ bias, float* __restrict__ C) {
  const int tid = threadIdx.x, w = tid >> 6, l = tid & 63;
  const int wm = w >> 1, wn = w & 1;
  const int m0 = blockIdx.x * 128, n0 = blockIdx.y * 128;
  const int fr = l & 15, kg = (l >> 4) * 8;
  f4 acc[4][4] = {};
  for (int s = 0; s < 8; ++s) {
    const int k0 = s * 32 + kg;
    sv8 ah[4], al[4], bh[4], bl[4];
#pragma unroll
    for (int t = 0; t < 4; ++t) {
      const short* ap = A2 + (size_t)(m0 + wm * 64 + t * 16 + fr) * 512 + k0;
      ah[t] = *(const sv8*)ap;
      al[t] = *(const sv8*)(ap + 256);
      split8(W + (size_t)(n0 + wn * 64 + t * 16 + fr) * 256 + k0, bh[t], bl[t]);
    }
#pragma unroll
    for (int mt = 0; mt < 4; ++mt)
#pragma unroll
      for (int nt = 0; nt < 4; ++nt) {
        f4 a0 = acc[mt][nt];
        a0 = mfma16(ah[mt], bh[nt], a0);
        a0 = mfma16(al[mt], bh[nt], a0);
        a0 = mfma16(ah[mt], bl[nt], a0);
        acc[mt][nt] = a0;
      }
  }
  const int r0 = (l >> 4) * 4;
#pragma unroll
  for (int mt = 0; mt < 4; ++mt)
#pragma unroll
    for (int nt = 0; nt < 4; ++nt) {
      const int n = n0 + wn * 64 + nt * 16 + fr;
      const float bv = bias[n];
      const size_t mb = (size_t)(m0 + wm * 64 + mt * 16 + r0);
#pragma unroll
      for (int j = 0; j < 4; ++j) C[(mb + j) * 256 + n] = acc[mt][nt][j] + bv;
    }
}

// LDS pointer with per-row XOR swizzle: float index d at byte (4d ^ ((d>>5&7)<<4)).
// 16B-aligned for d%4==0; bijective per 1 KiB row; kills the fixed-h 8-way conflict.
__device__ __forceinline__ float* ldsP(float* base, int row, int d) {
  return (float*)((char*)base + row * 1024 + ((4 * d) ^ (((d >> 5) & 7) << 4)));
}

// One block per (b, nb). 2 barriers; scores+softmax+gate+PV fused per-thread.
// Thread = (q, h, half): 16-dim partial dot completed via shfl_xor(.,1).
__global__ __launch_bounds__(256, 4) void attn_v3(
    const float* __restrict__ Qb, const float* __restrict__ Kb,
    const float* __restrict__ Vb, const int* __restrict__ amask,
    const float* __restrict__ efeat, const float* __restrict__ Wgate,
    const float* __restrict__ bgate, short* __restrict__ AO2) {
  __shared__ float Ks[KCNT * 256];  // swizzled rows, 17 KiB
  __shared__ float Vs[KCNT * 256];  // swizzled rows, 17 KiB

  const int tid = threadIdx.x, g = blockIdx.x;
  const int b = g >> 11, nb = g & (NB - 1);
  const size_t tok0 = (size_t)(b * N_SEQ + nb * LQ);

  // stage 16 leaf K,V rows (coalesced float4 -> swizzled LDS)
#pragma unroll
  for (int i = 0; i < 4; ++i) {
    const int f = tid + i * 256;
    const int t = f >> 6, c4 = (f & 63) * 4;
    *(float4*)ldsP(Ks, t, c4) = *(const float4*)(Kb + (tok0 + t) * 256 + c4);
    *(float4*)ldsP(Vs, t, c4) = *(const float4*)(Vb + (tok0 + t) * 256 + c4);
  }
  __syncthreads();
  {  // block-node row 16 = mean of 16 leaf rows (linearity of Wk/Wv + bias)
    float ks = 0.f, vs = 0.f;
#pragma unroll
    for (int t = 0; t < 16; ++t) {
      ks += *ldsP(Ks, t, tid);
      vs += *ldsP(Vs, t, tid);
    }
    *ldsP(Ks, 16, tid) = ks * 0.0625f;
    *ldsP(Vs, 16, tid) = vs * 0.0625f;
  }
  __syncthreads();

  // fused phase: thread (q = tid>>4, h = (tid>>1)&7, half = tid&1)
  const int q = tid >> 4, h = (tid >> 1) & 7, half = tid & 1;
  const int d0 = h * HD + half * 16;

  float qh[16];
  {
    const float* qp = Qb + (tok0 + q) * 256 + d0;
#pragma unroll
    for (int j = 0; j < 4; ++j) {
      float4 v = *(const float4*)(qp + j * 4);
      qh[j * 4] = v.x; qh[j * 4 + 1] = v.y;
      qh[j * 4 + 2] = v.z; qh[j * 4 + 3] = v.w;
    }
  }
  const float wg0 = Wgate[h * 4], wg1 = Wgate[h * 4 + 1];
  const float wg2 = Wgate[h * 4 + 2], wg3 = Wgate[h * 4 + 3];
  const float bg = bgate[h];
  const float* eb = efeat + (size_t)(nb * LQ + q) * KCNT * 4;
  const int* mrow = amask + (size_t)(nb * LQ + q) * KCNT;

  float sc[KCNT], gt[KCNT];
  unsigned vis = 0;
  float mx = -1e30f;
#pragma unroll
  for (int kc = 0; kc < KCNT; ++kc) {
    float dot = 0.f;
#pragma unroll
    for (int j = 0; j < 4; ++j) {
      float4 kv = *(const float4*)ldsP(Ks, kc, d0 + j * 4);
      dot += qh[j * 4] * kv.x + qh[j * 4 + 1] * kv.y +
             qh[j * 4 + 2] * kv.z + qh[j * 4 + 3] * kv.w;
    }
    dot += __shfl_xor(dot, 1);  // combine the two 16-dim halves
    float e0, e1, e2, e3;
    if (kc == 16 || kc == q) { e0 = e1 = e2 = 0.f; e3 = 1.f; }
    else { float4 e = *(const float4*)(eb + kc * 4); e0 = e.x; e1 = e.y; e2 = e.z; e3 = e.w; }
    const int m = mrow[kc];
    const float s = dot * SCALE_F + e3;
    sc[kc] = s;
    if (m) { vis |= (1u << kc); mx = fmaxf(mx, s); }
    gt[kc] = m ? (e0 * wg0 + e1 * wg1 + e2 * wg2 + e3 * wg3 + bg) : 0.f;
  }
  float den = 0.f;
#pragma unroll
  for (int kc = 0; kc < KCNT; ++kc) {
    const float pv = (vis & (1u << kc)) ? expf(sc[kc] - mx) : 0.f;
    sc[kc] = pv;
    den += pv;
  }
  const float inv = 1.f / den;
#pragma unroll
  for (int kc = 0; kc < KCNT; ++kc) sc[kc] = sc[kc] * inv + gt[kc];

  float o[16] = {};
  for (int kc = 0; kc < KCNT; ++kc) {
    const float c = sc[kc];
#pragma unroll
    for (int j = 0; j < 4; ++j) {
      float4 vv = *(const float4*)ldsP(Vs, kc, d0 + j * 4);
      o[j * 4] += c * vv.x;
      o[j * 4 + 1] += c * vv.y;
      o[j * 4 + 2] += c * vv.z;
      o[j * 4 + 3] += c * vv.w;
    }
  }
  // hi|lo bf16 output overlays the Q buffer; this wave is the only reader
  // and writer of rows tok0+q (reads above precede writes in program order).
  short* ao = AO2 + (tok0 + q) * 512 + d0;
  sv8 hi, lo;
#pragma unroll
  for (int e = 0; e < 8; ++e) {
    const short hb = f2bf(o[e]);
    hi[e] = hb;
    lo[e] = f2bf(o[e] - bf2f(hb));
  }
  *(sv8*)ao = hi;
  *(sv8*)&ao[256] = lo;
#pragma unroll
  for (int e = 0; e < 8; ++e) {
    const short hb = f2bf(o[8 + e]);
    hi[e] = hb;
    lo[e] = f2bf(o[8 + e] - bf2f(hb));
  }
  *(sv8*)&ao[8] = hi;
  *(sv8*)&ao[264] = lo;
}

extern "C" void kernel_launch(void* const* d_in, const int* in_sizes, int n_in,
                              void* d_out, int out_size, void* d_ws, size_t ws_size,
                              hipStream_t stream) {
  const float* x = (const float*)d_in[0];
  const int* amask = (const int*)d_in[1];
  const float* efeat = (const float*)d_in[2];
  const float* Wqkv = (const float*)d_in[3];
  const float* bqkv = (const float*)d_in[4];
  const float* Wproj = (const float*)d_in[5];
  const float* bproj = (const float*)d_in[6];
  const float* Wgate = (const float*)d_in[7];
  const float* bgate = (const float*)d_in[8];
  float* out = (float*)d_out;

  char* ws = (char*)d_ws;
  const size_t QSZ = (size_t)M_ROWS * 256 * 4;  // 64 MiB
  const size_t W2Q_SZ = (size_t)768 * 512 * 2;
  const size_t W2P_SZ = (size_t)256 * 512 * 2;

  if (ws_size >= 3 * QSZ + W2Q_SZ + W2P_SZ) {
    short* X2 = (short*)ws;
    float* Qb = (float*)(ws + QSZ);
    float* Kb = (float*)(ws + 2 * QSZ);
    short* W2Q = (short*)(ws + 3 * QSZ);
    short* W2P = (short*)(ws + 3 * QSZ + W2Q_SZ);
    float* Vb = out;
    split256<<<dim3(M_ROWS * 64 / 256), 256, 0, stream>>>(x, X2, M_ROWS * 64);
    split256<<<dim3(768 * 64 / 256), 256, 0, stream>>>(Wqkv, W2Q, 768 * 64);
    split256<<<dim3(256 * 64 / 256), 256, 0, stream>>>(Wproj, W2P, 256 * 64);
    gemm_pre_qkv<<<dim3(M_ROWS / 128, 6), 256, 0, stream>>>(X2, W2Q, bqkv, Qb, Kb, Vb);
    attn_v3<<<dim3(B_SZ * NB), 256, 0, stream>>>(Qb, Kb, Vb, amask, efeat,
                                                 Wgate, bgate, (short*)Qb);
    gemm_pre_out<<<dim3(M_ROWS / 128, 2), 256, 0, stream>>>((const short*)Qb,
                                                            W2P, bproj, out);
  } else {
    if (ws_size < 2 * QSZ) return;
    float* Qb = (float*)ws;
    float* Kb = (float*)(ws + QSZ);
    float* Vb = out;
    gemm_qkv<<<dim3(M_ROWS / 128, 6), 256, 0, stream>>>(x, Wqkv, bqkv, Qb, Kb, Vb);
    attn_v3<<<dim3(B_SZ * NB), 256, 0, stream>>>(Qb, Kb, Vb, amask, efeat,
                                                 Wgate, bgate, (short*)Qb);
    gemm_out<<<dim3(M_ROWS / 128, 2), 256, 0, stream>>>((const short*)Qb, Wproj,
                                                        bproj, out);
  }
}